// Round 2
// baseline (11262.665 us; speedup 1.0000x reference)
//
#include <hip/hip_runtime.h>
#include <hip/hip_bf16.h>
#include <math.h>

#define N_NODES 100000
#define N_EDGES 3200000
#define IN_DIM 512
#define HID 64
#define N_CLASSES 7
#define LAYERS 32
#define ALPHA 0.1f
#define THETA 0.5f

#define CDIV(a, b) (((a) + (b) - 1) / (b))

// ---------------- edge dtype detection (int32 vs int64 storage) ----------------
// If edge_index is stored as int64 little-endian, the high 32-bit word of every
// element is 0 (values < 2^17). For int32 storage, words 1,3,5,... are genuine
// src indices (each zero with prob 1e-5) -> 16 consecutive zeros is conclusive.
__global__ void k_detect(const unsigned int* __restrict__ ei, int* __restrict__ flag) {
    if (threadIdx.x == 0 && blockIdx.x == 0) {
        int is64 = 1;
        for (int i = 0; i < 16; i++)
            if (ei[2 * i + 1] != 0u) { is64 = 0; break; }
        *flag = is64;
    }
}

__device__ __forceinline__ int edge_elem(const int* ei, int is64, int idx) {
    return is64 ? ei[2 * (long long)idx] : ei[idx];
}

// ---------------- degree histogram ----------------
__global__ void k_zero_cnt(int* __restrict__ cnt) {
    int i = blockIdx.x * blockDim.x + threadIdx.x;
    if (i < N_NODES) cnt[i] = 0;
}

__global__ void k_count(const int* __restrict__ ei, const int* __restrict__ flag,
                        int* __restrict__ cnt) {
    int is64 = *flag;
    int e = blockIdx.x * blockDim.x + threadIdx.x;
    if (e >= N_EDGES) return;
    int d = edge_elem(ei, is64, N_EDGES + e);
    atomicAdd(&cnt[d], 1);
}

__global__ void k_dinv(const int* __restrict__ cnt, float* __restrict__ dinv) {
    int i = blockIdx.x * blockDim.x + threadIdx.x;
    if (i < N_NODES) dinv[i] = rsqrtf((float)(cnt[i] + 1));  // +1 self-loop
}

// ---------------- exclusive scan over cnt -> row_start ----------------
#define SCAN_T 256
#define SCAN_ELEMS 1024

__global__ void k_scan1(const int* __restrict__ cnt, int* __restrict__ rs,
                        int* __restrict__ bsum) {
    __shared__ int sh[SCAN_T];
    int t = threadIdx.x;
    int base = blockIdx.x * SCAN_ELEMS + t * 4;
    int v0 = (base + 0 < N_NODES) ? cnt[base + 0] : 0;
    int v1 = (base + 1 < N_NODES) ? cnt[base + 1] : 0;
    int v2 = (base + 2 < N_NODES) ? cnt[base + 2] : 0;
    int v3 = (base + 3 < N_NODES) ? cnt[base + 3] : 0;
    int ts = v0 + v1 + v2 + v3;
    sh[t] = ts;
    __syncthreads();
    for (int off = 1; off < SCAN_T; off <<= 1) {
        int x = 0;
        if (t >= off) x = sh[t - off];
        __syncthreads();
        if (t >= off) sh[t] += x;
        __syncthreads();
    }
    int excl = sh[t] - ts;
    if (t == SCAN_T - 1) bsum[blockIdx.x] = sh[t];
    int run = excl;
    if (base + 0 < N_NODES) rs[base + 0] = run; run += v0;
    if (base + 1 < N_NODES) rs[base + 1] = run; run += v1;
    if (base + 2 < N_NODES) rs[base + 2] = run; run += v2;
    if (base + 3 < N_NODES) rs[base + 3] = run;
}

__global__ void k_scan2(const int* __restrict__ bsum, int* __restrict__ bofs, int nb) {
    __shared__ int sh[256];
    int t = threadIdx.x;
    int v = (t < nb) ? bsum[t] : 0;
    sh[t] = v;
    __syncthreads();
    for (int off = 1; off < 256; off <<= 1) {
        int x = 0;
        if (t >= off) x = sh[t - off];
        __syncthreads();
        if (t >= off) sh[t] += x;
        __syncthreads();
    }
    if (t < nb) bofs[t] = sh[t] - v;
}

__global__ void k_scan3(int* __restrict__ rs, const int* __restrict__ bofs,
                        int* __restrict__ fill) {
    int i = blockIdx.x * blockDim.x + threadIdx.x;
    if (i < N_NODES) {
        rs[i] += bofs[i / SCAN_ELEMS];
        fill[i] = 0;
    }
    if (i == 0) rs[N_NODES] = N_EDGES;
}

// ---------------- CSR scatter (sorted by dst) ----------------
__global__ void k_scatter(const int* __restrict__ ei, const int* __restrict__ flag,
                          const int* __restrict__ rs, int* __restrict__ fill,
                          int* __restrict__ ssrc) {
    int is64 = *flag;
    int e = blockIdx.x * blockDim.x + threadIdx.x;
    if (e >= N_EDGES) return;
    int s = edge_elem(ei, is64, e);
    int d = edge_elem(ei, is64, N_EDGES + e);
    int pos = rs[d] + atomicAdd(&fill[d], 1);
    ssrc[pos] = s;
}

// ---------------- h0 = relu(x @ W0 + b0) : M=100000, K=512, N=64 ----------------
__global__ __launch_bounds__(256) void k_h0(const float* __restrict__ x,
                                            const float* __restrict__ W0,
                                            const float* __restrict__ b0,
                                            float* __restrict__ h0) {
    __shared__ float xs[32][68];  // transposed x tile: [k][m], pad 68
    __shared__ float ws[32][68];  // W0 tile: [k][n]
    int t = threadIdx.x;
    int row0 = blockIdx.x * 64;
    int tm = t >> 4, tn = t & 15;
    float acc[4][4] = {};

    for (int k0 = 0; k0 < IN_DIM; k0 += 32) {
        // load 64 rows x 32 k of x, store transposed
        #pragma unroll
        for (int j = 0; j < 2; j++) {
            int lin = t + j * 256;
            int r = lin >> 3, c4 = lin & 7;
            int row = row0 + r;
            float4 v = make_float4(0.f, 0.f, 0.f, 0.f);
            if (row < N_NODES)
                v = *(const float4*)&x[(size_t)row * IN_DIM + k0 + c4 * 4];
            xs[c4 * 4 + 0][r] = v.x;
            xs[c4 * 4 + 1][r] = v.y;
            xs[c4 * 4 + 2][r] = v.z;
            xs[c4 * 4 + 3][r] = v.w;
        }
        // load 32 k x 64 n of W0
        #pragma unroll
        for (int j = 0; j < 2; j++) {
            int lin = t + j * 256;
            int kr = lin >> 4, c4 = lin & 15;
            *(float4*)&ws[kr][c4 * 4] = *(const float4*)&W0[(size_t)(k0 + kr) * HID + c4 * 4];
        }
        __syncthreads();
        #pragma unroll
        for (int kk = 0; kk < 32; kk++) {
            float4 av = *(const float4*)&xs[kk][tm * 4];
            float4 bv = *(const float4*)&ws[kk][tn * 4];
            float a4[4] = {av.x, av.y, av.z, av.w};
            float b4[4] = {bv.x, bv.y, bv.z, bv.w};
            #pragma unroll
            for (int i = 0; i < 4; i++)
                #pragma unroll
                for (int j = 0; j < 4; j++)
                    acc[i][j] = fmaf(a4[i], b4[j], acc[i][j]);
        }
        __syncthreads();
    }
    #pragma unroll
    for (int i = 0; i < 4; i++) {
        int row = row0 + tm * 4 + i;
        if (row < N_NODES) {
            float4 o;
            o.x = fmaxf(acc[i][0] + b0[tn * 4 + 0], 0.f);
            o.y = fmaxf(acc[i][1] + b0[tn * 4 + 1], 0.f);
            o.z = fmaxf(acc[i][2] + b0[tn * 4 + 2], 0.f);
            o.w = fmaxf(acc[i][3] + b0[tn * 4 + 3], 0.f);
            *(float4*)&h0[(size_t)row * HID + tn * 4] = o;
        }
    }
}

// ---------------- one GCN2 layer: agg + residual + 64x64 GEMM + relu ----------------
// norm factorization: sum_e dinv[s]*dinv[n]*h[s] = dinv[n] * sum_e dinv[s]*h[s]
#define NODES_PER_BLOCK 32
#define LWAVES 4
__global__ __launch_bounds__(256) void k_layer(
    const float* __restrict__ hin, const float* __restrict__ h0,
    float* __restrict__ hout, const float* __restrict__ W,
    const int* __restrict__ rs, const int* __restrict__ ssrc,
    const float* __restrict__ dinv, float beta) {
    __shared__ float Ws[HID][HID + 1];  // [f][j], pad 65 -> conflict-free column reads
    __shared__ float ow[LWAVES][HID];
    int t = threadIdx.x;
    // stage W (4096 floats, 16 per thread)
    #pragma unroll
    for (int j = 0; j < 16; j++) {
        int lin = t + j * 256;
        Ws[lin >> 6][lin & 63] = W[lin];
    }
    __syncthreads();

    int w = t >> 6, lane = t & 63;
    int nbase = blockIdx.x * NODES_PER_BLOCK + w * (NODES_PER_BLOCK / LWAVES);
    #pragma unroll 1
    for (int ni = 0; ni < NODES_PER_BLOCK / LWAVES; ni++) {
        int n = nbase + ni;  // N_NODES divisible by 32 -> always in range
        float dn = dinv[n];
        float acc = dn * hin[(size_t)n * HID + lane];  // self-loop (dinv[n]*h[n])
        int e0 = rs[n], e1 = rs[n + 1];
        for (int e = e0; e < e1; e++) {
            int s = ssrc[e];
            acc = fmaf(dinv[s], hin[(size_t)s * HID + lane], acc);
        }
        acc *= dn;
        float out = 0.9f * acc + 0.1f * h0[(size_t)n * HID + lane];
        ow[w][lane] = out;
        __builtin_amdgcn_wave_barrier();  // keep DS write before DS reads (in-order per wave)
        float acc2 = 0.f;
        #pragma unroll
        for (int f = 0; f < HID; f += 4) {
            float4 o4 = *(const float4*)&ow[w][f];  // wave-broadcast
            acc2 = fmaf(o4.x, Ws[f + 0][lane], acc2);
            acc2 = fmaf(o4.y, Ws[f + 1][lane], acc2);
            acc2 = fmaf(o4.z, Ws[f + 2][lane], acc2);
            acc2 = fmaf(o4.w, Ws[f + 3][lane], acc2);
        }
        __builtin_amdgcn_wave_barrier();
        float hn = beta * acc2 + (1.f - beta) * out;
        hout[(size_t)n * HID + lane] = fmaxf(hn, 0.f);
    }
}

// ---------------- out = h @ Wout + bout ----------------
__global__ __launch_bounds__(256) void k_final(const float* __restrict__ h,
                                               const float* __restrict__ Wout,
                                               const float* __restrict__ bout,
                                               float* __restrict__ out) {
    int t = threadIdx.x;
    int w = t >> 6, lane = t & 63;
    int n = blockIdx.x * 4 + w;
    if (n >= N_NODES) return;
    float hv = h[(size_t)n * HID + lane];
    #pragma unroll
    for (int c = 0; c < N_CLASSES; c++) {
        float p = hv * Wout[lane * N_CLASSES + c];
        #pragma unroll
        for (int off = 32; off > 0; off >>= 1) p += __shfl_xor(p, off);
        if (lane == 0) out[(size_t)n * N_CLASSES + c] = p + bout[c];
    }
}

extern "C" void kernel_launch(void* const* d_in, const int* in_sizes, int n_in,
                              void* d_out, int out_size, void* d_ws, size_t ws_size,
                              hipStream_t stream) {
    const float* x    = (const float*)d_in[0];
    const int*   ei   = (const int*)d_in[1];
    const float* W0   = (const float*)d_in[2];
    const float* b0   = (const float*)d_in[3];
    const float* Wl   = (const float*)d_in[4];
    const float* Wout = (const float*)d_in[5];
    const float* bout = (const float*)d_in[6];
    float* out = (float*)d_out;

    char* ws = (char*)d_ws;
    size_t off = 0;
    auto alloc = [&](size_t bytes) -> void* {
        void* p = ws + off;
        off += (bytes + 511) & ~(size_t)511;
        return p;
    };
    int*   flag  = (int*)alloc(4);
    int*   cnt   = (int*)alloc((size_t)N_NODES * 4);   // reused as `fill` after scan1
    float* dinv  = (float*)alloc((size_t)N_NODES * 4);
    int*   rs    = (int*)alloc((size_t)(N_NODES + 1) * 4);
    int*   bsum  = (int*)alloc(1024 * 4);
    int*   bofs  = (int*)alloc(1024 * 4);
    int*   ssrc  = (int*)alloc((size_t)N_EDGES * 4);
    float* h0    = (float*)alloc((size_t)N_NODES * HID * 4);
    float* hA    = (float*)alloc((size_t)N_NODES * HID * 4);
    float* hB    = (float*)alloc((size_t)N_NODES * HID * 4);
    int* fill = cnt;  // alias: cnt is dead after k_scan1/k_dinv

    int nb_scan = CDIV(N_NODES, SCAN_ELEMS);  // 98

    k_detect<<<1, 64, 0, stream>>>((const unsigned int*)ei, flag);
    k_zero_cnt<<<CDIV(N_NODES, 256), 256, 0, stream>>>(cnt);
    k_count<<<CDIV(N_EDGES, 256), 256, 0, stream>>>(ei, flag, cnt);
    k_dinv<<<CDIV(N_NODES, 256), 256, 0, stream>>>(cnt, dinv);
    k_scan1<<<nb_scan, SCAN_T, 0, stream>>>(cnt, rs, bsum);
    k_scan2<<<1, 256, 0, stream>>>(bsum, bofs, nb_scan);
    k_scan3<<<CDIV(N_NODES, 256), 256, 0, stream>>>(rs, bofs, fill);
    k_scatter<<<CDIV(N_EDGES, 256), 256, 0, stream>>>(ei, flag, rs, fill, ssrc);

    k_h0<<<CDIV(N_NODES, 64), 256, 0, stream>>>(x, W0, b0, h0);

    const float* hin = h0;
    float* ho = hA;
    for (int l = 0; l < LAYERS; l++) {
        float beta = logf(THETA / (float)(l + 1) + 1.0f);
        k_layer<<<N_NODES / NODES_PER_BLOCK, 256, 0, stream>>>(
            hin, h0, ho, Wl + (size_t)l * HID * HID, rs, ssrc, dinv, beta);
        hin = ho;
        ho = (hin == hA) ? hB : hA;
    }

    k_final<<<CDIV(N_NODES, 4), 256, 0, stream>>>(hin, Wout, bout, out);
}

// Round 3
// 4738.824 us; speedup vs baseline: 2.3767x; 2.3767x over previous
//
#include <hip/hip_runtime.h>
#include <hip/hip_bf16.h>
#include <math.h>

#define N_NODES 100000
#define N_EDGES 3200000
#define IN_DIM 512
#define HID 64
#define N_CLASSES 7
#define LAYERS 32
#define ALPHA 0.1f
#define THETA 0.5f

#define CDIV(a, b) (((a) + (b) - 1) / (b))

// ---------------- edge dtype detection (int32 vs int64 storage) ----------------
__global__ void k_detect(const unsigned int* __restrict__ ei, int* __restrict__ flag) {
    if (threadIdx.x == 0 && blockIdx.x == 0) {
        int is64 = 1;
        for (int i = 0; i < 16; i++)
            if (ei[2 * i + 1] != 0u) { is64 = 0; break; }
        *flag = is64;
    }
}

__device__ __forceinline__ int edge_elem(const int* ei, int is64, int idx) {
    return is64 ? ei[2 * (long long)idx] : ei[idx];
}

// ---------------- degree histogram ----------------
__global__ void k_zero_cnt(int* __restrict__ cnt) {
    int i = blockIdx.x * blockDim.x + threadIdx.x;
    if (i < N_NODES) cnt[i] = 0;
}

__global__ void k_count(const int* __restrict__ ei, const int* __restrict__ flag,
                        int* __restrict__ cnt) {
    int is64 = *flag;
    int e = blockIdx.x * blockDim.x + threadIdx.x;
    if (e >= N_EDGES) return;
    int d = edge_elem(ei, is64, N_EDGES + e);
    atomicAdd(&cnt[d], 1);
}

__global__ void k_dinv(const int* __restrict__ cnt, float* __restrict__ dinv) {
    int i = blockIdx.x * blockDim.x + threadIdx.x;
    if (i < N_NODES) dinv[i] = rsqrtf((float)(cnt[i] + 1));  // +1 self-loop
}

// ---------------- exclusive scan over cnt -> row_start ----------------
#define SCAN_T 256
#define SCAN_ELEMS 1024

__global__ void k_scan1(const int* __restrict__ cnt, int* __restrict__ rs,
                        int* __restrict__ bsum) {
    __shared__ int sh[SCAN_T];
    int t = threadIdx.x;
    int base = blockIdx.x * SCAN_ELEMS + t * 4;
    int v0 = (base + 0 < N_NODES) ? cnt[base + 0] : 0;
    int v1 = (base + 1 < N_NODES) ? cnt[base + 1] : 0;
    int v2 = (base + 2 < N_NODES) ? cnt[base + 2] : 0;
    int v3 = (base + 3 < N_NODES) ? cnt[base + 3] : 0;
    int ts = v0 + v1 + v2 + v3;
    sh[t] = ts;
    __syncthreads();
    for (int off = 1; off < SCAN_T; off <<= 1) {
        int x = 0;
        if (t >= off) x = sh[t - off];
        __syncthreads();
        if (t >= off) sh[t] += x;
        __syncthreads();
    }
    int excl = sh[t] - ts;
    if (t == SCAN_T - 1) bsum[blockIdx.x] = sh[t];
    int run = excl;
    if (base + 0 < N_NODES) rs[base + 0] = run; run += v0;
    if (base + 1 < N_NODES) rs[base + 1] = run; run += v1;
    if (base + 2 < N_NODES) rs[base + 2] = run; run += v2;
    if (base + 3 < N_NODES) rs[base + 3] = run;
}

__global__ void k_scan2(const int* __restrict__ bsum, int* __restrict__ bofs, int nb) {
    __shared__ int sh[256];
    int t = threadIdx.x;
    int v = (t < nb) ? bsum[t] : 0;
    sh[t] = v;
    __syncthreads();
    for (int off = 1; off < 256; off <<= 1) {
        int x = 0;
        if (t >= off) x = sh[t - off];
        __syncthreads();
        if (t >= off) sh[t] += x;
        __syncthreads();
    }
    if (t < nb) bofs[t] = sh[t] - v;
}

__global__ void k_scan3(int* __restrict__ rs, const int* __restrict__ bofs,
                        int* __restrict__ fill) {
    int i = blockIdx.x * blockDim.x + threadIdx.x;
    if (i < N_NODES) {
        rs[i] += bofs[i / SCAN_ELEMS];
        fill[i] = 0;
    }
    if (i == 0) rs[N_NODES] = N_EDGES;
}

// ---------------- CSR scatter (sorted by dst) ----------------
__global__ void k_scatter(const int* __restrict__ ei, const int* __restrict__ flag,
                          const int* __restrict__ rs, int* __restrict__ fill,
                          int* __restrict__ ssrc) {
    int is64 = *flag;
    int e = blockIdx.x * blockDim.x + threadIdx.x;
    if (e >= N_EDGES) return;
    int s = edge_elem(ei, is64, e);
    int d = edge_elem(ei, is64, N_EDGES + e);
    int pos = rs[d] + atomicAdd(&fill[d], 1);
    ssrc[pos] = s;
}

// ---------------- h0 = relu(x @ W0 + b0); also hs0 = dinv * h0 ----------------
__global__ __launch_bounds__(256) void k_h0(const float* __restrict__ x,
                                            const float* __restrict__ W0,
                                            const float* __restrict__ b0,
                                            const float* __restrict__ dinv,
                                            float* __restrict__ h0,
                                            float* __restrict__ hs0) {
    __shared__ float xs[32][68];  // transposed x tile: [k][m]
    __shared__ float ws[32][68];  // W0 tile: [k][n]
    int t = threadIdx.x;
    int row0 = blockIdx.x * 64;
    int tm = t >> 4, tn = t & 15;
    float acc[4][4] = {};

    for (int k0 = 0; k0 < IN_DIM; k0 += 32) {
        #pragma unroll
        for (int j = 0; j < 2; j++) {
            int lin = t + j * 256;
            int r = lin >> 3, c4 = lin & 7;
            int row = row0 + r;
            float4 v = make_float4(0.f, 0.f, 0.f, 0.f);
            if (row < N_NODES)
                v = *(const float4*)&x[(size_t)row * IN_DIM + k0 + c4 * 4];
            xs[c4 * 4 + 0][r] = v.x;
            xs[c4 * 4 + 1][r] = v.y;
            xs[c4 * 4 + 2][r] = v.z;
            xs[c4 * 4 + 3][r] = v.w;
        }
        #pragma unroll
        for (int j = 0; j < 2; j++) {
            int lin = t + j * 256;
            int kr = lin >> 4, c4 = lin & 15;
            *(float4*)&ws[kr][c4 * 4] = *(const float4*)&W0[(size_t)(k0 + kr) * HID + c4 * 4];
        }
        __syncthreads();
        #pragma unroll
        for (int kk = 0; kk < 32; kk++) {
            float4 av = *(const float4*)&xs[kk][tm * 4];
            float4 bv = *(const float4*)&ws[kk][tn * 4];
            float a4[4] = {av.x, av.y, av.z, av.w};
            float b4[4] = {bv.x, bv.y, bv.z, bv.w};
            #pragma unroll
            for (int i = 0; i < 4; i++)
                #pragma unroll
                for (int j = 0; j < 4; j++)
                    acc[i][j] = fmaf(a4[i], b4[j], acc[i][j]);
        }
        __syncthreads();
    }
    #pragma unroll
    for (int i = 0; i < 4; i++) {
        int row = row0 + tm * 4 + i;
        if (row < N_NODES) {
            float dn = dinv[row];
            float4 o;
            o.x = fmaxf(acc[i][0] + b0[tn * 4 + 0], 0.f);
            o.y = fmaxf(acc[i][1] + b0[tn * 4 + 1], 0.f);
            o.z = fmaxf(acc[i][2] + b0[tn * 4 + 2], 0.f);
            o.w = fmaxf(acc[i][3] + b0[tn * 4 + 3], 0.f);
            *(float4*)&h0[(size_t)row * HID + tn * 4] = o;
            float4 s;
            s.x = o.x * dn; s.y = o.y * dn; s.z = o.z * dn; s.w = o.w * dn;
            *(float4*)&hs0[(size_t)row * HID + tn * 4] = s;
        }
    }
}

// ---------------- one GCN2 layer on pre-scaled state hs = dinv*h ----------------
// agg = dinv[n] * (hs[n] + sum_e hs[src_e]);  out = 0.9*agg + 0.1*h0[n]
// h' = relu(beta*(out@W) + (1-beta)*out);  hs_out = dinv[n]*h'
#define NODES_PER_BLOCK 32
#define LWAVES 4
#define EB 8  // edge batch: 8 outstanding row-gathers per wave
__global__ __launch_bounds__(256) void k_layer(
    const float* __restrict__ hsin, const float* __restrict__ h0,
    float* __restrict__ hsout, const float* __restrict__ W,
    const int* __restrict__ rs, const int* __restrict__ ssrc,
    const float* __restrict__ dinv, float beta) {
    __shared__ float Ws[HID][HID + 1];
    __shared__ float ow[LWAVES][HID];
    int t = threadIdx.x;
    #pragma unroll
    for (int j = 0; j < 16; j++) {
        int lin = t + j * 256;
        Ws[lin >> 6][lin & 63] = W[lin];
    }
    __syncthreads();

    int w = t >> 6, lane = t & 63;
    int nbase = blockIdx.x * NODES_PER_BLOCK + w * (NODES_PER_BLOCK / LWAVES);
    #pragma unroll 1
    for (int ni = 0; ni < NODES_PER_BLOCK / LWAVES; ni++) {
        int n = nbase + ni;  // N_NODES % 32 == 0 -> in range
        float acc = hsin[(size_t)n * HID + lane];  // self-loop term
        int e0 = rs[n], e1 = rs[n + 1];
        int e = e0;
        // batched gather: 8 independent row loads in flight
        for (; e + EB <= e1; e += EB) {
            int s[EB];
            #pragma unroll
            for (int j = 0; j < EB; j++) s[j] = ssrc[e + j];
            float v[EB];
            #pragma unroll
            for (int j = 0; j < EB; j++) v[j] = hsin[(size_t)s[j] * HID + lane];
            #pragma unroll
            for (int j = 0; j < EB; j++) acc += v[j];
        }
        for (; e < e1; e++)
            acc += hsin[(size_t)ssrc[e] * HID + lane];

        float dn = dinv[n];
        float out = 0.9f * (dn * acc) + 0.1f * h0[(size_t)n * HID + lane];
        ow[w][lane] = out;
        __builtin_amdgcn_wave_barrier();  // DS write before DS reads (in-order per wave)
        float acc2 = 0.f;
        #pragma unroll
        for (int f = 0; f < HID; f += 4) {
            float4 o4 = *(const float4*)&ow[w][f];  // wave-broadcast
            acc2 = fmaf(o4.x, Ws[f + 0][lane], acc2);
            acc2 = fmaf(o4.y, Ws[f + 1][lane], acc2);
            acc2 = fmaf(o4.z, Ws[f + 2][lane], acc2);
            acc2 = fmaf(o4.w, Ws[f + 3][lane], acc2);
        }
        __builtin_amdgcn_wave_barrier();
        float hn = beta * acc2 + (1.f - beta) * out;
        hsout[(size_t)n * HID + lane] = dn * fmaxf(hn, 0.f);
    }
}

// ---------------- out = (hs/dinv) @ Wout + bout ----------------
__global__ __launch_bounds__(256) void k_final(const float* __restrict__ hs,
                                               const float* __restrict__ dinv,
                                               const float* __restrict__ Wout,
                                               const float* __restrict__ bout,
                                               float* __restrict__ out) {
    int t = threadIdx.x;
    int w = t >> 6, lane = t & 63;
    int n = blockIdx.x * 4 + w;
    if (n >= N_NODES) return;
    float hv = hs[(size_t)n * HID + lane] * (1.0f / dinv[n]);
    #pragma unroll
    for (int c = 0; c < N_CLASSES; c++) {
        float p = hv * Wout[lane * N_CLASSES + c];
        #pragma unroll
        for (int off = 32; off > 0; off >>= 1) p += __shfl_xor(p, off);
        if (lane == 0) out[(size_t)n * N_CLASSES + c] = p + bout[c];
    }
}

extern "C" void kernel_launch(void* const* d_in, const int* in_sizes, int n_in,
                              void* d_out, int out_size, void* d_ws, size_t ws_size,
                              hipStream_t stream) {
    const float* x    = (const float*)d_in[0];
    const int*   ei   = (const int*)d_in[1];
    const float* W0   = (const float*)d_in[2];
    const float* b0   = (const float*)d_in[3];
    const float* Wl   = (const float*)d_in[4];
    const float* Wout = (const float*)d_in[5];
    const float* bout = (const float*)d_in[6];
    float* out = (float*)d_out;

    char* ws = (char*)d_ws;
    size_t off = 0;
    auto alloc = [&](size_t bytes) -> void* {
        void* p = ws + off;
        off += (bytes + 511) & ~(size_t)511;
        return p;
    };
    int*   flag  = (int*)alloc(4);
    int*   cnt   = (int*)alloc((size_t)N_NODES * 4);   // reused as `fill` after scan1
    float* dinv  = (float*)alloc((size_t)N_NODES * 4);
    int*   rs    = (int*)alloc((size_t)(N_NODES + 1) * 4);
    int*   bsum  = (int*)alloc(1024 * 4);
    int*   bofs  = (int*)alloc(1024 * 4);
    int*   ssrc  = (int*)alloc((size_t)N_EDGES * 4);
    float* h0    = (float*)alloc((size_t)N_NODES * HID * 4);
    float* hsA   = (float*)alloc((size_t)N_NODES * HID * 4);
    float* hsB   = (float*)alloc((size_t)N_NODES * HID * 4);
    int* fill = cnt;  // alias: cnt is dead after k_scan1/k_dinv

    int nb_scan = CDIV(N_NODES, SCAN_ELEMS);  // 98

    k_detect<<<1, 64, 0, stream>>>((const unsigned int*)ei, flag);
    k_zero_cnt<<<CDIV(N_NODES, 256), 256, 0, stream>>>(cnt);
    k_count<<<CDIV(N_EDGES, 256), 256, 0, stream>>>(ei, flag, cnt);
    k_dinv<<<CDIV(N_NODES, 256), 256, 0, stream>>>(cnt, dinv);
    k_scan1<<<nb_scan, SCAN_T, 0, stream>>>(cnt, rs, bsum);
    k_scan2<<<1, 256, 0, stream>>>(bsum, bofs, nb_scan);
    k_scan3<<<CDIV(N_NODES, 256), 256, 0, stream>>>(rs, bofs, fill);
    k_scatter<<<CDIV(N_EDGES, 256), 256, 0, stream>>>(ei, flag, rs, fill, ssrc);

    k_h0<<<CDIV(N_NODES, 64), 256, 0, stream>>>(x, W0, b0, dinv, h0, hsA);

    const float* hin = hsA;
    float* ho = hsB;
    for (int l = 0; l < LAYERS; l++) {
        float beta = logf(THETA / (float)(l + 1) + 1.0f);
        k_layer<<<N_NODES / NODES_PER_BLOCK, 256, 0, stream>>>(
            hin, h0, ho, Wl + (size_t)l * HID * HID, rs, ssrc, dinv, beta);
        hin = ho;
        ho = (hin == hsA) ? hsB : hsA;
    }

    k_final<<<CDIV(N_NODES, 4), 256, 0, stream>>>(hin, dinv, Wout, bout, out);
}

// Round 6
// 4721.980 us; speedup vs baseline: 2.3852x; 1.0036x over previous
//
#include <hip/hip_runtime.h>
#include <hip/hip_bf16.h>
#include <math.h>

#define N_NODES 100000
#define N_EDGES 3200000
#define IN_DIM 512
#define HID 64
#define N_CLASSES 7
#define LAYERS 32
#define ALPHA 0.1f
#define THETA 0.5f

#define CDIV(a, b) (((a) + (b) - 1) / (b))

typedef unsigned int uint32;
typedef unsigned short ushort16;

// bf16 helpers (RNE pack, bit-shift unpack)
__device__ __forceinline__ ushort16 f2bf(float f) {
    union { float f; uint32 u; } x; x.f = f;
    uint32 r = x.u + 0x7FFFu + ((x.u >> 16) & 1u);
    return (ushort16)(r >> 16);
}
__device__ __forceinline__ float bflo(uint32 u) {
    union { uint32 u; float f; } x; x.u = u << 16; return x.f;
}
__device__ __forceinline__ float bfhi(uint32 u) {
    union { uint32 u; float f; } x; x.u = u & 0xFFFF0000u; return x.f;
}
__device__ __forceinline__ float bf2f(ushort16 s) {
    union { uint32 u; float f; } x; x.u = ((uint32)s) << 16; return x.f;
}

// ---------------- edge dtype detection (int32 vs int64 storage) ----------------
__global__ void k_detect(const unsigned int* __restrict__ ei, int* __restrict__ flag) {
    if (threadIdx.x == 0 && blockIdx.x == 0) {
        int is64 = 1;
        for (int i = 0; i < 16; i++)
            if (ei[2 * i + 1] != 0u) { is64 = 0; break; }
        *flag = is64;
    }
}

__device__ __forceinline__ int edge_elem(const int* ei, int is64, int idx) {
    return is64 ? ei[2 * (long long)idx] : ei[idx];
}

// ---------------- degree histogram ----------------
__global__ void k_zero_cnt(int* __restrict__ cnt) {
    int i = blockIdx.x * blockDim.x + threadIdx.x;
    if (i < N_NODES) cnt[i] = 0;
}

__global__ void k_count(const int* __restrict__ ei, const int* __restrict__ flag,
                        int* __restrict__ cnt) {
    int is64 = *flag;
    int e = blockIdx.x * blockDim.x + threadIdx.x;
    if (e >= N_EDGES) return;
    int d = edge_elem(ei, is64, N_EDGES + e);
    atomicAdd(&cnt[d], 1);
}

__global__ void k_dinv(const int* __restrict__ cnt, float* __restrict__ dinv) {
    int i = blockIdx.x * blockDim.x + threadIdx.x;
    if (i < N_NODES) dinv[i] = rsqrtf((float)(cnt[i] + 1));  // +1 self-loop
}

// ---------------- exclusive scan over cnt -> row_start ----------------
#define SCAN_T 256
#define SCAN_ELEMS 1024

__global__ void k_scan1(const int* __restrict__ cnt, int* __restrict__ rs,
                        int* __restrict__ bsum) {
    __shared__ int sh[SCAN_T];
    int t = threadIdx.x;
    int base = blockIdx.x * SCAN_ELEMS + t * 4;
    int v0 = (base + 0 < N_NODES) ? cnt[base + 0] : 0;
    int v1 = (base + 1 < N_NODES) ? cnt[base + 1] : 0;
    int v2 = (base + 2 < N_NODES) ? cnt[base + 2] : 0;
    int v3 = (base + 3 < N_NODES) ? cnt[base + 3] : 0;
    int ts = v0 + v1 + v2 + v3;
    sh[t] = ts;
    __syncthreads();
    for (int off = 1; off < SCAN_T; off <<= 1) {
        int x = 0;
        if (t >= off) x = sh[t - off];
        __syncthreads();
        if (t >= off) sh[t] += x;
        __syncthreads();
    }
    int excl = sh[t] - ts;
    if (t == SCAN_T - 1) bsum[blockIdx.x] = sh[t];
    int run = excl;
    if (base + 0 < N_NODES) rs[base + 0] = run; run += v0;
    if (base + 1 < N_NODES) rs[base + 1] = run; run += v1;
    if (base + 2 < N_NODES) rs[base + 2] = run; run += v2;
    if (base + 3 < N_NODES) rs[base + 3] = run;
}

__global__ void k_scan2(const int* __restrict__ bsum, int* __restrict__ bofs, int nb) {
    __shared__ int sh[256];
    int t = threadIdx.x;
    int v = (t < nb) ? bsum[t] : 0;
    sh[t] = v;
    __syncthreads();
    for (int off = 1; off < 256; off <<= 1) {
        int x = 0;
        if (t >= off) x = sh[t - off];
        __syncthreads();
        if (t >= off) sh[t] += x;
        __syncthreads();
    }
    if (t < nb) bofs[t] = sh[t] - v;
}

__global__ void k_scan3(int* __restrict__ rs, const int* __restrict__ bofs,
                        int* __restrict__ fill) {
    int i = blockIdx.x * blockDim.x + threadIdx.x;
    if (i < N_NODES) {
        rs[i] += bofs[i / SCAN_ELEMS];
        fill[i] = 0;
    }
    if (i == 0) rs[N_NODES] = N_EDGES;
}

// ---------------- CSR scatter (sorted by dst) ----------------
__global__ void k_scatter(const int* __restrict__ ei, const int* __restrict__ flag,
                          const int* __restrict__ rs, int* __restrict__ fill,
                          int* __restrict__ ssrc) {
    int is64 = *flag;
    int e = blockIdx.x * blockDim.x + threadIdx.x;
    if (e >= N_EDGES) return;
    int s = edge_elem(ei, is64, e);
    int d = edge_elem(ei, is64, N_EDGES + e);
    int pos = rs[d] + atomicAdd(&fill[d], 1);
    ssrc[pos] = s;
}

// ---------------- h0 = relu(x @ W0 + b0) [f32]; hs0 = dinv*h0 [bf16x2] ----------------
__global__ __launch_bounds__(256) void k_h0(const float* __restrict__ x,
                                            const float* __restrict__ W0,
                                            const float* __restrict__ b0,
                                            const float* __restrict__ dinv,
                                            float* __restrict__ h0,
                                            uint32* __restrict__ hs0) {
    __shared__ float xs[32][68];
    __shared__ float ws[32][68];
    int t = threadIdx.x;
    int row0 = blockIdx.x * 64;
    int tm = t >> 4, tn = t & 15;
    float acc[4][4] = {};

    for (int k0 = 0; k0 < IN_DIM; k0 += 32) {
        #pragma unroll
        for (int j = 0; j < 2; j++) {
            int lin = t + j * 256;
            int r = lin >> 3, c4 = lin & 7;
            int row = row0 + r;
            float4 v = make_float4(0.f, 0.f, 0.f, 0.f);
            if (row < N_NODES)
                v = *(const float4*)&x[(size_t)row * IN_DIM + k0 + c4 * 4];
            xs[c4 * 4 + 0][r] = v.x;
            xs[c4 * 4 + 1][r] = v.y;
            xs[c4 * 4 + 2][r] = v.z;
            xs[c4 * 4 + 3][r] = v.w;
        }
        #pragma unroll
        for (int j = 0; j < 2; j++) {
            int lin = t + j * 256;
            int kr = lin >> 4, c4 = lin & 15;
            *(float4*)&ws[kr][c4 * 4] = *(const float4*)&W0[(size_t)(k0 + kr) * HID + c4 * 4];
        }
        __syncthreads();
        #pragma unroll
        for (int kk = 0; kk < 32; kk++) {
            float4 av = *(const float4*)&xs[kk][tm * 4];
            float4 bv = *(const float4*)&ws[kk][tn * 4];
            float a4[4] = {av.x, av.y, av.z, av.w};
            float b4[4] = {bv.x, bv.y, bv.z, bv.w};
            #pragma unroll
            for (int i = 0; i < 4; i++)
                #pragma unroll
                for (int j = 0; j < 4; j++)
                    acc[i][j] = fmaf(a4[i], b4[j], acc[i][j]);
        }
        __syncthreads();
    }
    #pragma unroll
    for (int i = 0; i < 4; i++) {
        int row = row0 + tm * 4 + i;
        if (row < N_NODES) {
            float dn = dinv[row];
            float4 o;
            o.x = fmaxf(acc[i][0] + b0[tn * 4 + 0], 0.f);
            o.y = fmaxf(acc[i][1] + b0[tn * 4 + 1], 0.f);
            o.z = fmaxf(acc[i][2] + b0[tn * 4 + 2], 0.f);
            o.w = fmaxf(acc[i][3] + b0[tn * 4 + 3], 0.f);
            *(float4*)&h0[(size_t)row * HID + tn * 4] = o;
            uint32 p0 = (uint32)f2bf(o.x * dn) | ((uint32)f2bf(o.y * dn) << 16);
            uint32 p1 = (uint32)f2bf(o.z * dn) | ((uint32)f2bf(o.w * dn) << 16);
            uint2 pk; pk.x = p0; pk.y = p1;
            *(uint2*)&hs0[(size_t)row * 32 + tn * 2] = pk;
        }
    }
}

// ---------------- one GCN2 layer on bf16 pre-scaled state hs = dinv*h ----------------
// lane -> feature pair (2*(lane&31), +1); halves of the wave process even/odd edges
#define NODES_PER_BLOCK 32
#define LWAVES 4
#define EB 8  // 8 load instrs per batch x 2 rows each = 16 edges in flight
__global__ __launch_bounds__(256) void k_layer(
    const uint32* __restrict__ hsin, const float* __restrict__ h0,
    ushort16* __restrict__ hsout, const float* __restrict__ W,
    const int* __restrict__ rs, const int* __restrict__ ssrc,
    const float* __restrict__ dinv, float beta) {
    __shared__ float Ws[HID][HID + 1];
    __shared__ float ow[LWAVES][HID];
    int t = threadIdx.x;
    #pragma unroll
    for (int j = 0; j < 16; j++) {
        int lin = t + j * 256;
        Ws[lin >> 6][lin & 63] = W[lin];
    }
    __syncthreads();

    int w = t >> 6, lane = t & 63;
    int half = lane >> 5;   // 0: even edges, 1: odd edges
    int fl = lane & 31;     // feature-pair index
    int nbase = blockIdx.x * NODES_PER_BLOCK + w * (NODES_PER_BLOCK / LWAVES);
    #pragma unroll 1
    for (int ni = 0; ni < NODES_PER_BLOCK / LWAVES; ni++) {
        int n = nbase + ni;  // N_NODES % 32 == 0 -> in range
        float ax = 0.f, ay = 0.f;
        int e0 = rs[n], e1 = rs[n + 1];
        #pragma unroll 1
        for (int e = e0; e < e1; e += 2 * EB) {
            int   sj[EB];
            uint32 uj[EB];
            bool  okj[EB];
            #pragma unroll
            for (int j = 0; j < EB; j++) {
                int idx = e + 2 * j + half;
                okj[j] = idx < e1;
                sj[j] = okj[j] ? ssrc[idx] : 0;
            }
            #pragma unroll
            for (int j = 0; j < EB; j++)
                uj[j] = hsin[(size_t)sj[j] * 32 + fl];
            #pragma unroll
            for (int j = 0; j < EB; j++) {
                if (okj[j]) { ax += bflo(uj[j]); ay += bfhi(uj[j]); }
            }
        }
        // fold the two halves (even-edge sums + odd-edge sums)
        ax += __shfl_xor(ax, 32);
        ay += __shfl_xor(ay, 32);
        // self-loop term
        uint32 su = hsin[(size_t)n * 32 + fl];
        ax += bflo(su);
        ay += bfhi(su);
        float dn = dinv[n];
        float2 h0v = *(const float2*)&h0[(size_t)n * HID + fl * 2];
        float ox = 0.9f * (dn * ax) + 0.1f * h0v.x;
        float oy = 0.9f * (dn * ay) + 0.1f * h0v.y;
        if (lane < 32) *(float2*)&ow[w][fl * 2] = make_float2(ox, oy);
        __builtin_amdgcn_wave_barrier();  // DS write before DS reads (in-order per wave)
        float acc2 = 0.f;
        #pragma unroll
        for (int f = 0; f < HID; f += 4) {
            float4 o4 = *(const float4*)&ow[w][f];  // wave-broadcast
            acc2 = fmaf(o4.x, Ws[f + 0][lane], acc2);
            acc2 = fmaf(o4.y, Ws[f + 1][lane], acc2);
            acc2 = fmaf(o4.z, Ws[f + 2][lane], acc2);
            acc2 = fmaf(o4.w, Ws[f + 3][lane], acc2);
        }
        float oself = ow[w][lane];
        __builtin_amdgcn_wave_barrier();
        float hn = beta * acc2 + (1.f - beta) * oself;
        hsout[(size_t)n * HID + lane] = f2bf(dn * fmaxf(hn, 0.f));
    }
}

// ---------------- out = (hs/dinv) @ Wout + bout ----------------
__global__ __launch_bounds__(256) void k_final(const ushort16* __restrict__ hs,
                                               const float* __restrict__ dinv,
                                               const float* __restrict__ Wout,
                                               const float* __restrict__ bout,
                                               float* __restrict__ out) {
    int t = threadIdx.x;
    int w = t >> 6, lane = t & 63;
    int n = blockIdx.x * 4 + w;
    if (n >= N_NODES) return;
    float hv = bf2f(hs[(size_t)n * HID + lane]) * (1.0f / dinv[n]);
    #pragma unroll
    for (int c = 0; c < N_CLASSES; c++) {
        float p = hv * Wout[lane * N_CLASSES + c];
        #pragma unroll
        for (int off = 32; off > 0; off >>= 1) p += __shfl_xor(p, off);
        if (lane == 0) out[(size_t)n * N_CLASSES + c] = p + bout[c];
    }
}

extern "C" void kernel_launch(void* const* d_in, const int* in_sizes, int n_in,
                              void* d_out, int out_size, void* d_ws, size_t ws_size,
                              hipStream_t stream) {
    const float* x    = (const float*)d_in[0];
    const int*   ei   = (const int*)d_in[1];
    const float* W0   = (const float*)d_in[2];
    const float* b0   = (const float*)d_in[3];
    const float* Wl   = (const float*)d_in[4];
    const float* Wout = (const float*)d_in[5];
    const float* bout = (const float*)d_in[6];
    float* out = (float*)d_out;

    char* ws = (char*)d_ws;
    size_t off = 0;
    auto alloc = [&](size_t bytes) -> void* {
        void* p = ws + off;
        off += (bytes + 511) & ~(size_t)511;
        return p;
    };
    int*   flag  = (int*)alloc(4);
    int*   cnt   = (int*)alloc((size_t)N_NODES * 4);   // reused as `fill` after scan1
    float* dinv  = (float*)alloc((size_t)N_NODES * 4);
    int*   rs    = (int*)alloc((size_t)(N_NODES + 1) * 4);
    int*   bsum  = (int*)alloc(1024 * 4);
    int*   bofs  = (int*)alloc(1024 * 4);
    int*   ssrc  = (int*)alloc((size_t)N_EDGES * 4);
    float* h0    = (float*)alloc((size_t)N_NODES * HID * 4);
    void*  hsA   = alloc((size_t)N_NODES * HID * 2);   // bf16 state
    void*  hsB   = alloc((size_t)N_NODES * HID * 2);
    int* fill = cnt;  // alias: cnt is dead after k_scan1/k_dinv

    int nb_scan = CDIV(N_NODES, SCAN_ELEMS);  // 98

    k_detect<<<1, 64, 0, stream>>>((const unsigned int*)ei, flag);
    k_zero_cnt<<<CDIV(N_NODES, 256), 256, 0, stream>>>(cnt);
    k_count<<<CDIV(N_EDGES, 256), 256, 0, stream>>>(ei, flag, cnt);
    k_dinv<<<CDIV(N_NODES, 256), 256, 0, stream>>>(cnt, dinv);
    k_scan1<<<nb_scan, SCAN_T, 0, stream>>>(cnt, rs, bsum);
    k_scan2<<<1, 256, 0, stream>>>(bsum, bofs, nb_scan);
    k_scan3<<<CDIV(N_NODES, 256), 256, 0, stream>>>(rs, bofs, fill);
    k_scatter<<<CDIV(N_EDGES, 256), 256, 0, stream>>>(ei, flag, rs, fill, ssrc);

    k_h0<<<CDIV(N_NODES, 64), 256, 0, stream>>>(x, W0, b0, dinv, h0, (uint32*)hsA);

    const void* hin = hsA;
    void* ho = hsB;
    for (int l = 0; l < LAYERS; l++) {
        float beta = logf(THETA / (float)(l + 1) + 1.0f);
        k_layer<<<N_NODES / NODES_PER_BLOCK, 256, 0, stream>>>(
            (const uint32*)hin, h0, (ushort16*)ho, Wl + (size_t)l * HID * HID,
            rs, ssrc, dinv, beta);
        hin = ho;
        ho = (hin == hsA) ? hsB : hsA;
    }

    k_final<<<CDIV(N_NODES, 4), 256, 0, stream>>>((const ushort16*)hin, dinv, Wout, bout, out);
}